// Round 1
// baseline (221.390 us; speedup 1.0000x reference)
//
#include <hip/hip_runtime.h>

typedef unsigned short u16;
typedef unsigned int   u32;
typedef __attribute__((ext_vector_type(4))) float    floatx4;
typedef __attribute__((ext_vector_type(4))) unsigned uintx4;
typedef __attribute__((ext_vector_type(8))) __bf16   bf16x8;

#define MFMA16(a, b, c) __builtin_amdgcn_mfma_f32_16x16x32_bf16((a), (b), (c), 0, 0, 0)

__device__ __forceinline__ u16 f2bf(float f) {
    union { float f; u32 u; } v; v.f = f;
    u32 u = v.u;
    return (u16)((u + 0x7FFFu + ((u >> 16) & 1u)) >> 16);   // RNE
}

__device__ __forceinline__ bf16x8 ld_frag_lds(const u16* p) {
    uintx4 t = *(const uintx4*)p;
    return __builtin_bit_cast(bf16x8, t);
}
__device__ __forceinline__ bf16x8 ld_frag_g(const u16* p) {
    uintx4 t = *(const uintx4*)p;
    return __builtin_bit_cast(bf16x8, t);
}

// ---------------- prep: cast x (fp32 -> bf16) ----------------
__global__ __launch_bounds__(256) void cast_x_kernel(const float* __restrict__ x,
                                                     u16* __restrict__ Xb) {
    int idx = blockIdx.x * 256 + threadIdx.x;       // each handles 8 elements
    const float* src = x + (size_t)idx * 8;
    uintx4 o;
    u32 w0 = f2bf(src[0]) | ((u32)f2bf(src[1]) << 16);
    u32 w1 = f2bf(src[2]) | ((u32)f2bf(src[3]) << 16);
    u32 w2 = f2bf(src[4]) | ((u32)f2bf(src[5]) << 16);
    u32 w3 = f2bf(src[6]) | ((u32)f2bf(src[7]) << 16);
    o.x = w0; o.y = w1; o.z = w2; o.w = w3;
    *(uintx4*)(Xb + (size_t)idx * 8) = o;
}

// ---------------- prep: transpose + cast weights (W[k][n] -> WT[n][k]) ----------------
__global__ __launch_bounds__(256) void transpose_w_kernel(
        const float* __restrict__ Wq, const float* __restrict__ Wk,
        const float* __restrict__ Wv, const float* __restrict__ Wo,
        u16* __restrict__ WqT, u16* __restrict__ WkT,
        u16* __restrict__ WvT, u16* __restrict__ WoT) {
    int m = blockIdx.y;
    const float* W = (m == 0) ? Wq : (m == 1) ? Wk : (m == 2) ? Wv : Wo;
    u16* WT = (m == 0) ? WqT : (m == 1) ? WkT : (m == 2) ? WvT : WoT;
    int idx = blockIdx.x * 256 + threadIdx.x;       // 0..262143
    int n = idx >> 9, k = idx & 511;
    WT[idx] = f2bf(W[(size_t)k * 512 + n]);
}

// ---------------- fused QKV projection GEMM ----------------
// A = Xb (4096 x 512 bf16 row-major), Bt = W^T (512 x 512, n-major).
// n0 tile selects matrix (0=Q,1=K,2=V). Q,K stored (b,h,l,d); V stored (b,h,d,l).
__global__ __launch_bounds__(256) void gemm_qkv(
        const u16* __restrict__ Xb,
        const u16* __restrict__ WqT, const u16* __restrict__ WkT, const u16* __restrict__ WvT,
        const float* __restrict__ bq, const float* __restrict__ bk, const float* __restrict__ bv,
        u16* __restrict__ Qb, u16* __restrict__ Kb, u16* __restrict__ Vt) {
    __shared__ u16 As[64][72];
    __shared__ u16 Bs[64][72];
    int tid = threadIdx.x;
    int m0 = blockIdx.x * 64;
    int n0 = blockIdx.y * 64;                       // 0..1535
    int mat = n0 >> 9;                              // 0,1,2
    int ncol0 = n0 & 511;
    const u16* Bt = (mat == 0) ? WqT : (mat == 1) ? WkT : WvT;
    const float* bias = (mat == 0) ? bq : (mat == 1) ? bk : bv;

    int lane = tid & 63, w = tid >> 6, lo = lane & 15, hi = lane >> 4;
    floatx4 acc[4] = {};

    for (int kb = 0; kb < 8; kb++) {
        __syncthreads();
        for (int c = tid; c < 512; c += 256) {
            int row = c >> 3, cc = c & 7;
            *(uintx4*)&As[row][cc * 8] =
                *(const uintx4*)&Xb[(size_t)(m0 + row) * 512 + kb * 64 + cc * 8];
            *(uintx4*)&Bs[row][cc * 8] =
                *(const uintx4*)&Bt[(size_t)(ncol0 + row) * 512 + kb * 64 + cc * 8];
        }
        __syncthreads();
        for (int s = 0; s < 2; s++) {
            bf16x8 a = ld_frag_lds(&As[16 * w + lo][8 * hi + 32 * s]);
            for (int t = 0; t < 4; t++) {
                bf16x8 b = ld_frag_lds(&Bs[16 * t + lo][8 * hi + 32 * s]);
                acc[t] = MFMA16(a, b, acc[t]);
            }
        }
    }

    int h = ncol0 >> 6;
    for (int t = 0; t < 4; t++) {
        int dc = 16 * t + lo;
        float bval = bias[ncol0 + 16 * t + lo];
        for (int r = 0; r < 4; r++) {
            int mrow = m0 + 16 * w + 4 * hi + r;
            int bb = mrow >> 11, lrow = mrow & 2047;
            float v = acc[t][r] + bval;
            if (mat < 2) {
                u16* dst = (mat == 0) ? Qb : Kb;
                dst[((size_t)(bb * 8 + h) * 2048 + lrow) * 64 + dc] = f2bf(v);
            } else {
                Vt[((size_t)(bb * 8 + h) * 64 + dc) * 2048 + lrow] = f2bf(v);
            }
        }
    }
}

// ---------------- flash attention with bias/mask ----------------
// grid (L/64, B*H); block 256 = 4 waves; wave w handles queries [q0+16w, q0+16w+16)
__global__ __launch_bounds__(256) void flash_attn(
        const u16* __restrict__ Qb, const u16* __restrict__ Kb, const u16* __restrict__ Vt,
        const int* __restrict__ gap_ids, const int* __restrict__ dur_ids,
        const int* __restrict__ amask,
        const float* __restrict__ gap_emb, const float* __restrict__ dur_emb,
        u16* __restrict__ Ob) {
    __shared__ u16 Ks[64][72];
    __shared__ u16 Vs[64][72];      // Vs[d][key]
    __shared__ u16 Ps[4][16][72];   // per-wave P tile (16 queries x 64 keys)
    __shared__ float gapc[33];
    __shared__ float durc[17];
    __shared__ float keyb[64];
    __shared__ int gks[64];
    __shared__ int gqs[64];

    int tid = threadIdx.x;
    int lane = tid & 63, w = tid >> 6, lo = lane & 15, hi = lane >> 4;
    int q0 = blockIdx.x * 64;
    int bh = blockIdx.y;            // bb*8 + h
    int bb = bh >> 3, h = bh & 7;

    if (tid < 33) gapc[tid] = gap_emb[tid * 8 + h];
    if (tid >= 64 && tid < 81) durc[tid - 64] = dur_emb[(tid - 64) * 8 + h];
    if (tid >= 128 && tid < 192) gqs[tid - 128] = gap_ids[bb * 2048 + q0 + (tid - 128)];

    // Q fragments (stay in registers the whole kernel)
    size_t qbase = ((size_t)bh * 2048 + q0 + 16 * w + lo) * 64;
    bf16x8 aq0 = ld_frag_g(&Qb[qbase + 8 * hi]);
    bf16x8 aq1 = ld_frag_g(&Qb[qbase + 8 * hi + 32]);

    floatx4 O[4] = {};
    float m_r[4] = {-3e38f, -3e38f, -3e38f, -3e38f};
    float l_r[4] = {0.f, 0.f, 0.f, 0.f};
    const float scale = 0.125f;     // 1/sqrt(64)

    size_t kvbase = (size_t)bh * 2048 * 64;

    for (int kt = 0; kt < 32; kt++) {
        int k0 = kt * 64;
        __syncthreads();
        for (int c = tid; c < 512; c += 256) {
            int row = c >> 3, cc = c & 7;
            *(uintx4*)&Ks[row][cc * 8] =
                *(const uintx4*)&Kb[kvbase + (size_t)(k0 + row) * 64 + cc * 8];
            *(uintx4*)&Vs[row][cc * 8] =
                *(const uintx4*)&Vt[kvbase + (size_t)row * 2048 + k0 + cc * 8];
        }
        if (tid < 64) {
            int kk = k0 + tid;
            int msk = amask[bb * 2048 + kk];
            int did = dur_ids[bb * 2048 + kk];
            gks[tid] = gap_ids[bb * 2048 + kk];
            keyb[tid] = msk ? durc[did] : -2e9f;
        }
        __syncthreads();

        // S = Q K^T
        floatx4 sf[4] = {};
        for (int t = 0; t < 4; t++) {
            bf16x8 b0 = ld_frag_lds(&Ks[16 * t + lo][8 * hi]);
            sf[t] = MFMA16(aq0, b0, sf[t]);
            bf16x8 b1 = ld_frag_lds(&Ks[16 * t + lo][8 * hi + 32]);
            sf[t] = MFMA16(aq1, b1, sf[t]);
        }

        // scale + gap bias + key bias/mask
        int gq_r[4];
        for (int r = 0; r < 4; r++) gq_r[r] = gqs[16 * w + 4 * hi + r];
        float v[4][4];
        float mx[4] = {-3e38f, -3e38f, -3e38f, -3e38f};
        for (int t = 0; t < 4; t++) {
            int gk = gks[lo + 16 * t];
            float kb_ = keyb[lo + 16 * t];
            for (int r = 0; r < 4; r++) {
                int d = gq_r[r] - gk; d = d < 0 ? -d : d;
                float val = sf[t][r] * scale + gapc[d] + kb_;
                v[t][r] = val;
                mx[r] = fmaxf(mx[r], val);
            }
        }
        // row max across the 16 lanes holding the row
        for (int off = 1; off < 16; off <<= 1)
            for (int r = 0; r < 4; r++) mx[r] = fmaxf(mx[r], __shfl_xor(mx[r], off));

        float mnew[4], alpha[4], rsum[4];
        for (int r = 0; r < 4; r++) {
            mnew[r] = fmaxf(m_r[r], mx[r]);
            alpha[r] = __expf(m_r[r] - mnew[r]);
            m_r[r] = mnew[r];
            rsum[r] = 0.f;
        }
        for (int t = 0; t < 4; t++)
            for (int r = 0; r < 4; r++) {
                float p = __expf(v[t][r] - mnew[r]);
                rsum[r] += p;
                Ps[w][4 * hi + r][lo + 16 * t] = f2bf(p);
            }
        for (int off = 1; off < 16; off <<= 1)
            for (int r = 0; r < 4; r++) rsum[r] += __shfl_xor(rsum[r], off);
        for (int r = 0; r < 4; r++) l_r[r] = l_r[r] * alpha[r] + rsum[r];
        for (int t = 0; t < 4; t++)
            for (int r = 0; r < 4; r++) O[t][r] *= alpha[r];

        // make per-wave Ps writes visible to our own ds_reads
        asm volatile("s_waitcnt lgkmcnt(0)" ::: "memory");

        // O += P V   (P: A-layout from LDS; V: B-layout from Vs[d][key])
        bf16x8 pa0 = ld_frag_lds(&Ps[w][lo][8 * hi]);
        bf16x8 pa1 = ld_frag_lds(&Ps[w][lo][8 * hi + 32]);
        for (int t = 0; t < 4; t++) {
            bf16x8 vb0 = ld_frag_lds(&Vs[lo + 16 * t][8 * hi]);
            O[t] = MFMA16(pa0, vb0, O[t]);
            bf16x8 vb1 = ld_frag_lds(&Vs[lo + 16 * t][8 * hi + 32]);
            O[t] = MFMA16(pa1, vb1, O[t]);
        }
    }

    // normalize and write Ob (B*L x 512, heads concatenated)
    for (int t = 0; t < 4; t++)
        for (int r = 0; r < 4; r++) {
            int row = q0 + 16 * w + 4 * hi + r;
            int col = h * 64 + 16 * t + lo;
            Ob[((size_t)(bb * 2048 + row)) * 512 + col] = f2bf(O[t][r] / l_r[r]);
        }
}

// ---------------- output projection GEMM (bf16 in, fp32 out) ----------------
__global__ __launch_bounds__(256) void gemm_out(
        const u16* __restrict__ Ob, const u16* __restrict__ WoT,
        const float* __restrict__ bo, float* __restrict__ out) {
    __shared__ u16 As[64][72];
    __shared__ u16 Bs[64][72];
    int tid = threadIdx.x;
    int m0 = blockIdx.x * 64;
    int n0 = blockIdx.y * 64;
    int lane = tid & 63, w = tid >> 6, lo = lane & 15, hi = lane >> 4;
    floatx4 acc[4] = {};

    for (int kb = 0; kb < 8; kb++) {
        __syncthreads();
        for (int c = tid; c < 512; c += 256) {
            int row = c >> 3, cc = c & 7;
            *(uintx4*)&As[row][cc * 8] =
                *(const uintx4*)&Ob[(size_t)(m0 + row) * 512 + kb * 64 + cc * 8];
            *(uintx4*)&Bs[row][cc * 8] =
                *(const uintx4*)&WoT[(size_t)(n0 + row) * 512 + kb * 64 + cc * 8];
        }
        __syncthreads();
        for (int s = 0; s < 2; s++) {
            bf16x8 a = ld_frag_lds(&As[16 * w + lo][8 * hi + 32 * s]);
            for (int t = 0; t < 4; t++) {
                bf16x8 b = ld_frag_lds(&Bs[16 * t + lo][8 * hi + 32 * s]);
                acc[t] = MFMA16(a, b, acc[t]);
            }
        }
    }
    for (int t = 0; t < 4; t++) {
        int n = n0 + 16 * t + lo;
        float bval = bo[n];
        for (int r = 0; r < 4; r++) {
            int mrow = m0 + 16 * w + 4 * hi + r;
            out[(size_t)mrow * 512 + n] = acc[t][r] + bval;
        }
    }
}

extern "C" void kernel_launch(void* const* d_in, const int* in_sizes, int n_in,
                              void* d_out, int out_size, void* d_ws, size_t ws_size,
                              hipStream_t stream) {
    const float* x     = (const float*)d_in[0];
    const int*   amask = (const int*)d_in[1];
    const int*   gids  = (const int*)d_in[2];
    const int*   dids  = (const int*)d_in[3];
    const float* Wq    = (const float*)d_in[4];
    const float* bq    = (const float*)d_in[5];
    const float* Wk    = (const float*)d_in[6];
    const float* bk    = (const float*)d_in[7];
    const float* Wv    = (const float*)d_in[8];
    const float* bv    = (const float*)d_in[9];
    const float* Wo    = (const float*)d_in[10];
    const float* bo    = (const float*)d_in[11];
    const float* gap_emb = (const float*)d_in[12];
    const float* dur_emb = (const float*)d_in[13];
    float* out = (float*)d_out;

    char* ws = (char*)d_ws;
    u16* Xb  = (u16*)(ws + 0);
    u16* WqT = (u16*)(ws + 4194304);
    u16* WkT = (u16*)(ws + 4718592);
    u16* WvT = (u16*)(ws + 5242880);
    u16* WoT = (u16*)(ws + 5767168);
    u16* Qb  = (u16*)(ws + 6291456);
    u16* Kb  = (u16*)(ws + 10485760);
    u16* Vtr = (u16*)(ws + 14680064);
    u16* Ob  = (u16*)(ws + 18874368);

    hipLaunchKernelGGL(cast_x_kernel, dim3(1024), dim3(256), 0, stream, x, Xb);
    hipLaunchKernelGGL(transpose_w_kernel, dim3(1024, 4), dim3(256), 0, stream,
                       Wq, Wk, Wv, Wo, WqT, WkT, WvT, WoT);
    hipLaunchKernelGGL(gemm_qkv, dim3(64, 24), dim3(256), 0, stream,
                       Xb, WqT, WkT, WvT, bq, bk, bv, Qb, Kb, Vtr);
    hipLaunchKernelGGL(flash_attn, dim3(32, 16), dim3(256), 0, stream,
                       Qb, Kb, Vtr, gids, dids, amask, gap_emb, dur_emb, Ob);
    hipLaunchKernelGGL(gemm_out, dim3(64, 8), dim3(256), 0, stream,
                       Ob, WoT, bo, out);
}

// Round 2
// 186.650 us; speedup vs baseline: 1.1861x; 1.1861x over previous
//
#include <hip/hip_runtime.h>
#include <cmath>

typedef unsigned short u16;
typedef unsigned int   u32;
typedef __attribute__((ext_vector_type(4))) float    floatx4;
typedef __attribute__((ext_vector_type(4))) unsigned uintx4;
typedef __attribute__((ext_vector_type(8))) __bf16   bf16x8;

#define MFMA16(a, b, c) __builtin_amdgcn_mfma_f32_16x16x32_bf16((a), (b), (c), 0, 0, 0)

__device__ __forceinline__ u16 f2bf(float f) {
    union { float f; u32 u; } v; v.f = f;
    u32 u = v.u;
    return (u16)((u + 0x7FFFu + ((u >> 16) & 1u)) >> 16);   // RNE
}

__device__ __forceinline__ bf16x8 ld_frag(const u16* p) {
    uintx4 t = *(const uintx4*)p;
    return __builtin_bit_cast(bf16x8, t);
}

typedef __attribute__((address_space(3))) unsigned       lds_u32;
typedef __attribute__((address_space(1))) const unsigned glb_u32;
__device__ __forceinline__ void gl_lds16(const void* g, void* l) {
    __builtin_amdgcn_global_load_lds((glb_u32*)(uintptr_t)g, (lds_u32*)(uintptr_t)l, 16, 0, 0);
}

// log2(e) and 0.125*log2(e)
#define LOG2E   1.4426950408889634f
#define QSCALE  0.18033688011112043f

// ---------------- prep: cast x (fp32 -> bf16) ----------------
__global__ __launch_bounds__(256) void cast_x_kernel(const float* __restrict__ x,
                                                     u16* __restrict__ Xb) {
    int idx = blockIdx.x * 256 + threadIdx.x;
    const float* src = x + (size_t)idx * 8;
    uintx4 o;
    o.x = f2bf(src[0]) | ((u32)f2bf(src[1]) << 16);
    o.y = f2bf(src[2]) | ((u32)f2bf(src[3]) << 16);
    o.z = f2bf(src[4]) | ((u32)f2bf(src[5]) << 16);
    o.w = f2bf(src[6]) | ((u32)f2bf(src[7]) << 16);
    *(uintx4*)(Xb + (size_t)idx * 8) = o;
}

// ---------------- prep: transpose + cast weights ----------------
__global__ __launch_bounds__(256) void transpose_w_kernel(
        const float* __restrict__ Wq, const float* __restrict__ Wk,
        const float* __restrict__ Wv, const float* __restrict__ Wo,
        u16* __restrict__ WqT, u16* __restrict__ WkT,
        u16* __restrict__ WvT, u16* __restrict__ WoT) {
    int m = blockIdx.y;
    const float* W = (m == 0) ? Wq : (m == 1) ? Wk : (m == 2) ? Wv : Wo;
    u16* WT = (m == 0) ? WqT : (m == 1) ? WkT : (m == 2) ? WvT : WoT;
    int idx = blockIdx.x * 256 + threadIdx.x;
    int n = idx >> 9, k = idx & 511;
    WT[idx] = f2bf(W[(size_t)k * 512 + n]);
}

// ---------------- extras: Q_ext dims 64..127 (one-hot gap + const dur dim) ----------------
__global__ __launch_bounds__(256) void ext_q_kernel(const int* __restrict__ gap_ids,
                                                    u16* __restrict__ Qe) {
    int idx = blockIdx.x * 256 + threadIdx.x;   // bh*2048 + l
    int bh = idx >> 11, l = idx & 2047;
    int b = bh >> 3;
    int gq = gap_ids[b * 2048 + l];
    u16 lg = f2bf(LOG2E);
    u16* dst = Qe + (size_t)idx * 128;
    for (int ch = 8; ch < 16; ch++) {
        u16 vals[8];
        for (int e = 0; e < 8; e++) {
            int j = (ch - 8) * 8 + e;
            vals[e] = (j == gq || j == 33) ? lg : (u16)0;
        }
        *(uintx4*)(dst + ch * 8) = *(uintx4*)vals;
    }
}

// ---------------- extras: K_ext dims 64..127 (gapc column + dur/mask), chunk-swizzled ----------------
__global__ __launch_bounds__(256) void ext_k_kernel(const int* __restrict__ gap_ids,
                                                    const int* __restrict__ dur_ids,
                                                    const int* __restrict__ amask,
                                                    const float* __restrict__ gap_emb,
                                                    const float* __restrict__ dur_emb,
                                                    u16* __restrict__ Ke) {
    int idx = blockIdx.x * 256 + threadIdx.x;   // bh*2048 + l
    int bh = idx >> 11, l = idx & 2047;
    int b = bh >> 3, h = bh & 7;
    int gk = gap_ids[b * 2048 + l];
    int did = dur_ids[b * 2048 + l];
    int msk = amask[b * 2048 + l];
    float kval = msk ? dur_emb[did * 8 + h] : -1e9f;
    u16* dst = Ke + (size_t)idx * 128;
    int sw = l & 7;
    for (int ch = 8; ch < 16; ch++) {
        u16 vals[8];
        for (int e = 0; e < 8; e++) {
            int j = (ch - 8) * 8 + e;
            float v;
            if (j <= 32) { int d = j - gk; d = d < 0 ? -d : d; v = gap_emb[d * 8 + h]; }
            else if (j == 33) v = kval;
            else v = 0.f;
            vals[e] = f2bf(v);
        }
        int phys = 8 | ((ch & 7) ^ sw);
        *(uintx4*)(dst + phys * 8) = *(uintx4*)vals;
    }
}

// ---------------- fused QKV projection GEMM ----------------
// Q -> Qe[bh][l][0:64] scaled by 0.125*log2e; K -> Ke[bh][l][0:64] chunk-swizzled;
// V -> Vt[bh][d][2048] with per-64-key-group chunk swizzle.
__global__ __launch_bounds__(256) void gemm_qkv(
        const u16* __restrict__ Xb,
        const u16* __restrict__ WqT, const u16* __restrict__ WkT, const u16* __restrict__ WvT,
        const float* __restrict__ bq, const float* __restrict__ bk, const float* __restrict__ bv,
        u16* __restrict__ Qe, u16* __restrict__ Ke, u16* __restrict__ Vt) {
    __shared__ u16 As[64][72];
    __shared__ u16 Bs[64][72];
    int tid = threadIdx.x;
    int m0 = blockIdx.x * 64;
    int n0 = blockIdx.y * 64;
    int mat = n0 >> 9;
    int ncol0 = n0 & 511;
    const u16* Bt = (mat == 0) ? WqT : (mat == 1) ? WkT : WvT;
    const float* bias = (mat == 0) ? bq : (mat == 1) ? bk : bv;

    int lane = tid & 63, w = tid >> 6, lo = lane & 15, hi = lane >> 4;
    floatx4 acc[4] = {};

    for (int kb = 0; kb < 8; kb++) {
        __syncthreads();
        for (int c = tid; c < 512; c += 256) {
            int row = c >> 3, cc = c & 7;
            *(uintx4*)&As[row][cc * 8] =
                *(const uintx4*)&Xb[(size_t)(m0 + row) * 512 + kb * 64 + cc * 8];
            *(uintx4*)&Bs[row][cc * 8] =
                *(const uintx4*)&Bt[(size_t)(ncol0 + row) * 512 + kb * 64 + cc * 8];
        }
        __syncthreads();
        for (int s = 0; s < 2; s++) {
            bf16x8 a = ld_frag(&As[16 * w + lo][8 * hi + 32 * s]);
            for (int t = 0; t < 4; t++) {
                bf16x8 b = ld_frag(&Bs[16 * t + lo][8 * hi + 32 * s]);
                acc[t] = MFMA16(a, b, acc[t]);
            }
        }
    }

    int h = ncol0 >> 6;
    for (int t = 0; t < 4; t++) {
        int dc = 16 * t + lo;
        float bval = bias[ncol0 + dc];
        for (int r = 0; r < 4; r++) {
            int mrow = m0 + 16 * w + 4 * hi + r;
            int bb = mrow >> 11, lrow = mrow & 2047;
            float v = acc[t][r] + bval;
            size_t rowi = (size_t)(bb * 8 + h) * 2048 + lrow;
            if (mat == 0) {
                Qe[rowi * 128 + dc] = f2bf(v * QSCALE);
            } else if (mat == 1) {
                int phys = (((dc >> 3) ^ (lrow & 7)) << 3) | (dc & 7);
                Ke[rowi * 128 + phys] = f2bf(v);
            } else {
                int g = lrow >> 6, c = (lrow >> 3) & 7, e = lrow & 7;
                int col = (g << 6) | (((c ^ (dc & 7))) << 3) | e;
                Vt[((size_t)(bb * 8 + h) * 64 + dc) * 2048 + col] = f2bf(v);
            }
        }
    }
}

// ---------------- flash attention, bias pre-folded, no-max softmax, key-split x2 ----------------
// grid (32, 16, 2); block 256 = 4 waves; wave w: queries [q0+16w, q0+16w+16)
__global__ __launch_bounds__(256) void flash_attn(
        const u16* __restrict__ Qe, const u16* __restrict__ Ke, const u16* __restrict__ Vt,
        float* __restrict__ Opart, float* __restrict__ Lpart) {
    __shared__ u16 Ks[64 * 128];
    __shared__ u16 Vs[64 * 64];
    __shared__ u16 Ps[4 * 16 * 64];

    int tid = threadIdx.x, lane = tid & 63, w = tid >> 6, lo = lane & 15, hi = lane >> 4;
    int qt = blockIdx.x, bh = blockIdx.y, sp = blockIdx.z;
    int q0 = qt * 64;
    int sw = lo & 7;

    size_t qrow = ((size_t)bh * 2048 + q0 + 16 * w + lo) * 128;
    bf16x8 aq[4];
    for (int kc = 0; kc < 4; kc++) aq[kc] = ld_frag(&Qe[qrow + kc * 32 + hi * 8]);

    floatx4 O[4] = {};
    float l_r[4] = {0.f, 0.f, 0.f, 0.f};
    const u16* KeB = Ke + (size_t)bh * 2048 * 128;
    const u16* VtB = Vt + (size_t)bh * 64 * 2048;

    for (int kt = sp * 16; kt < sp * 16 + 16; kt++) {
        int k0 = kt * 64;
        __syncthreads();
        {   // K_ext tile: 16 KB contiguous
            const char* g = (const char*)(KeB + (size_t)k0 * 128);
            char* l = (char*)Ks;
            for (int r2 = 0; r2 < 4; r2++)
                gl_lds16(g + r2 * 4096 + tid * 16, l + r2 * 4096 + tid * 16);
        }
        {   // V tile: 64 rows x 128 B
            for (int p2 = 0; p2 < 2; p2++) {
                int c = p2 * 256 + tid;
                int row = c >> 3, ch = c & 7;
                const char* g = (const char*)(VtB + (size_t)row * 2048 + k0) + ch * 16;
                gl_lds16(g, (char*)Vs + c * 16);
            }
        }
        __syncthreads();

        // S = Qe * Ke^T (bias + scale + log2e already folded in)
        floatx4 sf[4] = {};
        for (int t = 0; t < 4; t++) {
            const u16* krow = &Ks[(16 * t + lo) * 128];
            for (int kc = 0; kc < 4; kc++) {
                int cc = kc * 4 + hi;
                int pc = (cc & 8) | ((cc & 7) ^ sw);
                bf16x8 b = ld_frag(&krow[pc * 8]);
                sf[t] = MFMA16(aq[kc], b, sf[t]);
            }
        }

        // P = 2^S ; accumulate per-lane l ; write P to LDS (swizzled)
        for (int t = 0; t < 4; t++) {
            int colc = 2 * t + (lo >> 3);
            int e = lo & 7;
            for (int r = 0; r < 4; r++) {
                float p = exp2f(sf[t][r]);
                l_r[r] += p;
                int rowp = 4 * hi + r;
                int pc = colc ^ (rowp & 7);
                Ps[(w * 16 + rowp) * 64 + pc * 8 + e] = f2bf(p);
            }
        }
        asm volatile("s_waitcnt lgkmcnt(0)" ::: "memory");

        // O += P V
        bf16x8 pa[2];
        for (int kc2 = 0; kc2 < 2; kc2++) {
            int pc = (kc2 * 4 + hi) ^ sw;
            pa[kc2] = ld_frag(&Ps[(w * 16 + lo) * 64 + pc * 8]);
        }
        for (int t = 0; t < 4; t++) {
            const u16* vrow = &Vs[(16 * t + lo) * 64];
            for (int kc2 = 0; kc2 < 2; kc2++) {
                int pc = (kc2 * 4 + hi) ^ sw;
                bf16x8 vb = ld_frag(&vrow[pc * 8]);
                O[t] = MFMA16(pa[kc2], vb, O[t]);
            }
        }
    }

    for (int off = 1; off < 16; off <<= 1)
        for (int r = 0; r < 4; r++) l_r[r] += __shfl_xor(l_r[r], off);

    size_t obase = (((size_t)sp * 16 + bh) * 32 + qt) * 4096;
    for (int t = 0; t < 4; t++)
        for (int r = 0; r < 4; r++)
            Opart[obase + (16 * w + 4 * hi + r) * 64 + 16 * t + lo] = O[t][r];
    if (lo == 0) {
        size_t lbase = (((size_t)sp * 16 + bh) * 32 + qt) * 64;
        for (int r = 0; r < 4; r++) Lpart[lbase + 16 * w + 4 * hi + r] = l_r[r];
    }
}

// ---------------- combine the 2 key-splits, normalize, cast to bf16 ----------------
__global__ __launch_bounds__(256) void combine_kernel(const float* __restrict__ Opart,
                                                      const float* __restrict__ Lpart,
                                                      u16* __restrict__ Ob) {
    int idx = blockIdx.x * 256 + threadIdx.x;   // 0..2097151
    int d = idx & 63;
    int q = (idx >> 6) & 2047;
    int bh = idx >> 17;
    int qt = q >> 6, qr = q & 63;
    size_t b0 = ((size_t)bh * 32 + qt) * 4096 + qr * 64 + d;
    float o = Opart[b0] + Opart[b0 + 2097152];
    size_t lb = ((size_t)bh * 32 + qt) * 64 + qr;
    float l = Lpart[lb] + Lpart[lb + 32768];
    int bb = bh >> 3, h = bh & 7;
    Ob[((size_t)(bb * 2048 + q)) * 512 + h * 64 + d] = f2bf(o / l);
}

// ---------------- output projection GEMM ----------------
__global__ __launch_bounds__(256) void gemm_out(
        const u16* __restrict__ Ob, const u16* __restrict__ WoT,
        const float* __restrict__ bo, float* __restrict__ out) {
    __shared__ u16 As[64][72];
    __shared__ u16 Bs[64][72];
    int tid = threadIdx.x;
    int m0 = blockIdx.x * 64;
    int n0 = blockIdx.y * 64;
    int lane = tid & 63, w = tid >> 6, lo = lane & 15, hi = lane >> 4;
    floatx4 acc[4] = {};

    for (int kb = 0; kb < 8; kb++) {
        __syncthreads();
        for (int c = tid; c < 512; c += 256) {
            int row = c >> 3, cc = c & 7;
            *(uintx4*)&As[row][cc * 8] =
                *(const uintx4*)&Ob[(size_t)(m0 + row) * 512 + kb * 64 + cc * 8];
            *(uintx4*)&Bs[row][cc * 8] =
                *(const uintx4*)&WoT[(size_t)(n0 + row) * 512 + kb * 64 + cc * 8];
        }
        __syncthreads();
        for (int s = 0; s < 2; s++) {
            bf16x8 a = ld_frag(&As[16 * w + lo][8 * hi + 32 * s]);
            for (int t = 0; t < 4; t++) {
                bf16x8 b = ld_frag(&Bs[16 * t + lo][8 * hi + 32 * s]);
                acc[t] = MFMA16(a, b, acc[t]);
            }
        }
    }
    for (int t = 0; t < 4; t++) {
        int n = n0 + 16 * t + lo;
        float bval = bo[n];
        for (int r = 0; r < 4; r++) {
            int mrow = m0 + 16 * w + 4 * hi + r;
            out[(size_t)mrow * 512 + n] = acc[t][r] + bval;
        }
    }
}

extern "C" void kernel_launch(void* const* d_in, const int* in_sizes, int n_in,
                              void* d_out, int out_size, void* d_ws, size_t ws_size,
                              hipStream_t stream) {
    const float* x     = (const float*)d_in[0];
    const int*   amask = (const int*)d_in[1];
    const int*   gids  = (const int*)d_in[2];
    const int*   dids  = (const int*)d_in[3];
    const float* Wq    = (const float*)d_in[4];
    const float* bq    = (const float*)d_in[5];
    const float* Wk    = (const float*)d_in[6];
    const float* bk    = (const float*)d_in[7];
    const float* Wv    = (const float*)d_in[8];
    const float* bv    = (const float*)d_in[9];
    const float* Wo    = (const float*)d_in[10];
    const float* bo    = (const float*)d_in[11];
    const float* gap_emb = (const float*)d_in[12];
    const float* dur_emb = (const float*)d_in[13];
    float* out = (float*)d_out;

    char* ws = (char*)d_ws;
    u16*   Qe    = (u16*)(ws + 0);            // 8.4 MB
    u16*   Ke    = (u16*)(ws + 8388608);      // 8.4 MB
    u16*   Vt    = (u16*)(ws + 16777216);     // 4.2 MB
    float* Opart = (float*)(ws + 20971520);   // 16.8 MB
    float* Lpart = (float*)(ws + 37748736);   // 0.26 MB
    u16*   Ob    = (u16*)(ws + 38010880);     // 4.2 MB
    u16*   WoT   = (u16*)(ws + 42205184);     // 0.5 MB
    // stage-1 scratch aliased inside Opart (dead before flash_attn writes it)
    u16*   Xb    = (u16*)(ws + 20971520);     // 4 MB
    u16*   WqT   = (u16*)(ws + 25165824);
    u16*   WkT   = (u16*)(ws + 25690112);
    u16*   WvT   = (u16*)(ws + 26214400);

    hipLaunchKernelGGL(cast_x_kernel, dim3(1024), dim3(256), 0, stream, x, Xb);
    hipLaunchKernelGGL(transpose_w_kernel, dim3(1024, 4), dim3(256), 0, stream,
                       Wq, Wk, Wv, Wo, WqT, WkT, WvT, WoT);
    hipLaunchKernelGGL(gemm_qkv, dim3(64, 24), dim3(256), 0, stream,
                       Xb, WqT, WkT, WvT, bq, bk, bv, Qe, Ke, Vt);
    hipLaunchKernelGGL(ext_q_kernel, dim3(128), dim3(256), 0, stream, gids, Qe);
    hipLaunchKernelGGL(ext_k_kernel, dim3(128), dim3(256), 0, stream,
                       gids, dids, amask, gap_emb, dur_emb, Ke);
    hipLaunchKernelGGL(flash_attn, dim3(32, 16, 2), dim3(256), 0, stream,
                       Qe, Ke, Vt, Opart, Lpart);
    hipLaunchKernelGGL(combine_kernel, dim3(8192), dim3(256), 0, stream,
                       Opart, Lpart, Ob);
    hipLaunchKernelGGL(gemm_out, dim3(64, 8), dim3(256), 0, stream,
                       Ob, WoT, bo, out);
}

// Round 3
// 175.894 us; speedup vs baseline: 1.2587x; 1.0611x over previous
//
#include <hip/hip_runtime.h>
#include <cmath>

typedef unsigned short u16;
typedef unsigned int   u32;
typedef __attribute__((ext_vector_type(2))) unsigned uintx2;
typedef __attribute__((ext_vector_type(4))) float    floatx4;
typedef __attribute__((ext_vector_type(4))) unsigned uintx4;
typedef __attribute__((ext_vector_type(8))) __bf16   bf16x8;

#define MFMA16(a, b, c) __builtin_amdgcn_mfma_f32_16x16x32_bf16((a), (b), (c), 0, 0, 0)

__device__ __forceinline__ u16 f2bf(float f) {
    union { float f; u32 u; } v; v.f = f;
    u32 u = v.u;
    return (u16)((u + 0x7FFFu + ((u >> 16) & 1u)) >> 16);   // RNE
}

__device__ __forceinline__ bf16x8 ld_frag(const u16* p) {
    uintx4 t = *(const uintx4*)p;
    return __builtin_bit_cast(bf16x8, t);
}

#if __has_builtin(__builtin_amdgcn_exp2f)
#define EXP2F(x) __builtin_amdgcn_exp2f(x)
#else
#define EXP2F(x) exp2f(x)
#endif

typedef __attribute__((address_space(3))) unsigned       lds_u32;
typedef __attribute__((address_space(1))) const unsigned glb_u32;
__device__ __forceinline__ void gl_lds16(const void* g, void* l) {
    __builtin_amdgcn_global_load_lds((glb_u32*)(uintptr_t)g, (lds_u32*)(uintptr_t)l, 16, 0, 0);
}

// log2(e) and 0.125*log2(e)
#define LOG2E   1.4426950408889634f
#define QSCALE  0.18033688011112043f

// ---------------- prep: cast x (fp32 -> bf16) ----------------
__global__ __launch_bounds__(256) void cast_x_kernel(const float* __restrict__ x,
                                                     u16* __restrict__ Xb) {
    int idx = blockIdx.x * 256 + threadIdx.x;
    const float* src = x + (size_t)idx * 8;
    uintx4 o;
    o.x = f2bf(src[0]) | ((u32)f2bf(src[1]) << 16);
    o.y = f2bf(src[2]) | ((u32)f2bf(src[3]) << 16);
    o.z = f2bf(src[4]) | ((u32)f2bf(src[5]) << 16);
    o.w = f2bf(src[6]) | ((u32)f2bf(src[7]) << 16);
    *(uintx4*)(Xb + (size_t)idx * 8) = o;
}

// ---------------- prep: transpose + cast weights ----------------
__global__ __launch_bounds__(256) void transpose_w_kernel(
        const float* __restrict__ Wq, const float* __restrict__ Wk,
        const float* __restrict__ Wv, const float* __restrict__ Wo,
        u16* __restrict__ WqT, u16* __restrict__ WkT,
        u16* __restrict__ WvT, u16* __restrict__ WoT) {
    int m = blockIdx.y;
    const float* W = (m == 0) ? Wq : (m == 1) ? Wk : (m == 2) ? Wv : Wo;
    u16* WT = (m == 0) ? WqT : (m == 1) ? WkT : (m == 2) ? WvT : WoT;
    int idx = blockIdx.x * 256 + threadIdx.x;
    int n = idx >> 9, k = idx & 511;
    WT[idx] = f2bf(W[(size_t)k * 512 + n]);
}

// ---------------- extras: Q_ext dims 64..127 (one-hot gap + const dur dim) ----------------
__global__ __launch_bounds__(256) void ext_q_kernel(const int* __restrict__ gap_ids,
                                                    u16* __restrict__ Qe) {
    int idx = blockIdx.x * 256 + threadIdx.x;   // bh*2048 + l
    int bh = idx >> 11, l = idx & 2047;
    int b = bh >> 3;
    int gq = gap_ids[b * 2048 + l];
    u16 lg = f2bf(LOG2E);
    u16* dst = Qe + (size_t)idx * 128;
    for (int ch = 8; ch < 16; ch++) {
        u16 vals[8];
        for (int e = 0; e < 8; e++) {
            int j = (ch - 8) * 8 + e;
            vals[e] = (j == gq || j == 33) ? lg : (u16)0;
        }
        *(uintx4*)(dst + ch * 8) = *(uintx4*)vals;
    }
}

// ---------------- extras: K_ext dims 64..127 (gapc column + dur/mask), chunk-swizzled ----------------
__global__ __launch_bounds__(256) void ext_k_kernel(const int* __restrict__ gap_ids,
                                                    const int* __restrict__ dur_ids,
                                                    const int* __restrict__ amask,
                                                    const float* __restrict__ gap_emb,
                                                    const float* __restrict__ dur_emb,
                                                    u16* __restrict__ Ke) {
    int idx = blockIdx.x * 256 + threadIdx.x;   // bh*2048 + l
    int bh = idx >> 11, l = idx & 2047;
    int b = bh >> 3, h = bh & 7;
    int gk = gap_ids[b * 2048 + l];
    int did = dur_ids[b * 2048 + l];
    int msk = amask[b * 2048 + l];
    float kval = msk ? dur_emb[did * 8 + h] : -1e9f;
    u16* dst = Ke + (size_t)idx * 128;
    int sw = l & 7;
    for (int ch = 8; ch < 16; ch++) {
        u16 vals[8];
        for (int e = 0; e < 8; e++) {
            int j = (ch - 8) * 8 + e;
            float v;
            if (j <= 32) { int d = j - gk; d = d < 0 ? -d : d; v = gap_emb[d * 8 + h]; }
            else if (j == 33) v = kval;
            else v = 0.f;
            vals[e] = f2bf(v);
        }
        int phys = 8 | ((ch & 7) ^ sw);
        *(uintx4*)(dst + phys * 8) = *(uintx4*)vals;
    }
}

// ---------------- fused QKV projection GEMM ----------------
// Q -> Qe[bh][l][0:64] scaled by 0.125*log2e; K -> Ke[bh][l][0:64] chunk(8)-swizzled;
// V -> Vt[bh][d][2048] with per-64-key chunk(4) swizzle keyed by d&15.
__global__ __launch_bounds__(256) void gemm_qkv(
        const u16* __restrict__ Xb,
        const u16* __restrict__ WqT, const u16* __restrict__ WkT, const u16* __restrict__ WvT,
        const float* __restrict__ bq, const float* __restrict__ bk, const float* __restrict__ bv,
        u16* __restrict__ Qe, u16* __restrict__ Ke, u16* __restrict__ Vt) {
    __shared__ u16 As[64][72];
    __shared__ u16 Bs[64][72];
    int tid = threadIdx.x;
    int m0 = blockIdx.x * 64;
    int n0 = blockIdx.y * 64;
    int mat = n0 >> 9;
    int ncol0 = n0 & 511;
    const u16* Bt = (mat == 0) ? WqT : (mat == 1) ? WkT : WvT;
    const float* bias = (mat == 0) ? bq : (mat == 1) ? bk : bv;

    int lane = tid & 63, w = tid >> 6, lo = lane & 15, hi = lane >> 4;
    floatx4 acc[4] = {};

    for (int kb = 0; kb < 8; kb++) {
        __syncthreads();
        for (int c = tid; c < 512; c += 256) {
            int row = c >> 3, cc = c & 7;
            *(uintx4*)&As[row][cc * 8] =
                *(const uintx4*)&Xb[(size_t)(m0 + row) * 512 + kb * 64 + cc * 8];
            *(uintx4*)&Bs[row][cc * 8] =
                *(const uintx4*)&Bt[(size_t)(ncol0 + row) * 512 + kb * 64 + cc * 8];
        }
        __syncthreads();
        for (int s = 0; s < 2; s++) {
            bf16x8 a = ld_frag(&As[16 * w + lo][8 * hi + 32 * s]);
            for (int t = 0; t < 4; t++) {
                bf16x8 b = ld_frag(&Bs[16 * t + lo][8 * hi + 32 * s]);
                acc[t] = MFMA16(a, b, acc[t]);
            }
        }
    }

    int h = ncol0 >> 6;
    for (int t = 0; t < 4; t++) {
        int dc = 16 * t + lo;
        float bval = bias[ncol0 + dc];
        for (int r = 0; r < 4; r++) {
            int mrow = m0 + 16 * w + 4 * hi + r;
            int bb = mrow >> 11, lrow = mrow & 2047;
            float v = acc[t][r] + bval;
            size_t rowi = (size_t)(bb * 8 + h) * 2048 + lrow;
            if (mat == 0) {
                Qe[rowi * 128 + dc] = f2bf(v * QSCALE);
            } else if (mat == 1) {
                int phys = (((dc >> 3) ^ (lrow & 7)) << 3) | (dc & 7);
                Ke[rowi * 128 + phys] = f2bf(v);
            } else {
                int kl = lrow & 63;
                int cl = kl >> 2, e2 = kl & 3;
                int pos = (lrow & ~63) | (((cl ^ (dc & 15)) << 2) | e2);
                Vt[((size_t)(bb * 8 + h) * 64 + dc) * 2048 + pos] = f2bf(v);
            }
        }
    }
}

// ---------------- flash attention: S^T trick, P stays in registers ----------------
// grid (32, 16, 3); block 256 = 4 waves; wave w: queries [q0+16w, q0+16w+16)
// S^T = K_ext * Q_ext^T  -> lane holds P[query=lo][key=16t+4hi+r]
// PV via 16x16x32 MFMA with k' = 8hi+j <-> key = 16*(j>>2)+4hi+(j&3)
__global__ __launch_bounds__(256, 6) void flash_attn(
        const u16* __restrict__ Qe, const u16* __restrict__ Ke, const u16* __restrict__ Vt,
        float* __restrict__ Opart, float* __restrict__ Lpart) {
    __shared__ u16 Ks[64 * 128];   // 16 KB
    __shared__ u16 Vs[64 * 64];    // 8 KB, [d][key] chunk(4)-swizzled by d&15

    int tid = threadIdx.x, lane = tid & 63, w = tid >> 6, lo = lane & 15, hi = lane >> 4;
    int qt = blockIdx.x, bh = blockIdx.y, sp = blockIdx.z;
    int q0 = qt * 64;
    int sw = lo & 7;

    // Q b-frags: lane n=lo <-> query q0+16w+lo (stay in registers)
    size_t qrow = ((size_t)bh * 2048 + q0 + 16 * w + lo) * 128;
    bf16x8 bq_[4];
    for (int kc = 0; kc < 4; kc++) bq_[kc] = ld_frag(&Qe[qrow + kc * 32 + hi * 8]);

    floatx4 O[4] = {};          // O[u][r]: query=4hi+r, d=16u+lo
    float l_acc = 0.f;          // per-lane partial sum for query=lo
    const u16* KeB = Ke + (size_t)bh * 2048 * 128;
    const u16* VtB = Vt + (size_t)bh * 64 * 2048;

    int kbeg = (sp * 32) / 3, kend = ((sp + 1) * 32) / 3;
    for (int kt = kbeg; kt < kend; kt++) {
        int k0 = kt * 64;
        __syncthreads();
        {   // K_ext tile: 16 KB contiguous
            const char* g = (const char*)(KeB + (size_t)k0 * 128);
            char* l = (char*)Ks;
            for (int r2 = 0; r2 < 4; r2++)
                gl_lds16(g + r2 * 4096 + tid * 16, l + r2 * 4096 + tid * 16);
        }
        {   // V tile: 64 d-rows x 128 B
            for (int p2 = 0; p2 < 2; p2++) {
                int c = p2 * 256 + tid;
                int row = c >> 3, ch = c & 7;
                const char* g = (const char*)(VtB + (size_t)row * 2048 + k0) + ch * 16;
                gl_lds16(g, (char*)Vs + c * 16);
            }
        }
        __syncthreads();

        // S^T = K * Q^T: A = K_ext rows (key=16t+lo), B = Q frags
        floatx4 sf[4] = {};
        for (int t = 0; t < 4; t++) {
            const u16* krow = &Ks[(16 * t + lo) * 128];
            for (int kc = 0; kc < 4; kc++) {
                int cc = kc * 4 + hi;
                int pc = (cc & 8) | ((cc & 7) ^ sw);
                bf16x8 a = ld_frag(&krow[pc * 8]);
                sf[t] = MFMA16(a, bq_[kc], sf[t]);
            }
        }

        // P = 2^S, pack to bf16 pairs in registers (round-half-up)
        u32 pk[4][2];
        for (int t = 0; t < 4; t++) {
            float p0 = EXP2F(sf[t][0]);
            float p1 = EXP2F(sf[t][1]);
            float p2 = EXP2F(sf[t][2]);
            float p3 = EXP2F(sf[t][3]);
            l_acc += (p0 + p1) + (p2 + p3);
            u32 u0 = __builtin_bit_cast(u32, p0) + 0x8000u;
            u32 u1 = __builtin_bit_cast(u32, p1) + 0x8000u;
            u32 u2 = __builtin_bit_cast(u32, p2) + 0x8000u;
            u32 u3 = __builtin_bit_cast(u32, p3) + 0x8000u;
            pk[t][0] = __builtin_amdgcn_perm(u1, u0, 0x07060302);  // (bf(p1)<<16)|bf(p0)
            pk[t][1] = __builtin_amdgcn_perm(u3, u2, 0x07060302);
        }

        // O += P V : A-frag = packed P (k'=8hi+j <-> key=16(j>>2)+4hi+(j&3))
        for (int tp = 0; tp < 2; tp++) {
            uintx4 av;
            av.x = pk[2 * tp][0]; av.y = pk[2 * tp][1];
            av.z = pk[2 * tp + 1][0]; av.w = pk[2 * tp + 1][1];
            bf16x8 af = __builtin_bit_cast(bf16x8, av);
            for (int u = 0; u < 4; u++) {
                const u16* vrow = &Vs[(16 * u + lo) * 64];
                int c0 = (8 * tp + hi) ^ lo;        // keys 32tp+4hi+(0..3)
                int c1 = (8 * tp + 4 + hi) ^ lo;    // keys 32tp+16+4hi+(0..3)
                uintx2 lo64 = *(const uintx2*)&vrow[c0 * 4];
                uintx2 hi64 = *(const uintx2*)&vrow[c1 * 4];
                uintx4 bv;
                bv.x = lo64.x; bv.y = lo64.y; bv.z = hi64.x; bv.w = hi64.y;
                O[u] = MFMA16(af, __builtin_bit_cast(bf16x8, bv), O[u]);
            }
        }
    }

    // complete l (sum over hi-groups: keys 4hi+r tile across lanes lo, lo+16, lo+32, lo+48)
    l_acc += __shfl_xor(l_acc, 16);
    l_acc += __shfl_xor(l_acc, 32);

    size_t obase = (((size_t)sp * 16 + bh) * 32 + qt) * 4096;
    for (int u = 0; u < 4; u++)
        for (int r = 0; r < 4; r++)
            Opart[obase + (size_t)(16 * w + 4 * hi + r) * 64 + 16 * u + lo] = O[u][r];
    if (hi == 0)
        Lpart[(((size_t)sp * 16 + bh) * 32 + qt) * 64 + 16 * w + lo] = l_acc;
}

// ---------------- combine the 3 key-splits, normalize, cast to bf16 ----------------
__global__ __launch_bounds__(256) void combine_kernel(const float* __restrict__ Opart,
                                                      const float* __restrict__ Lpart,
                                                      u16* __restrict__ Ob) {
    int idx = blockIdx.x * 256 + threadIdx.x;   // 0..2097151
    int d = idx & 63;
    int q = (idx >> 6) & 2047;
    int bh = idx >> 17;
    int qt = q >> 6, qr = q & 63;
    size_t b0 = ((size_t)bh * 32 + qt) * 4096 + qr * 64 + d;
    float o = Opart[b0] + Opart[b0 + 2097152] + Opart[b0 + 2 * 2097152];
    size_t lb = ((size_t)bh * 32 + qt) * 64 + qr;
    float l = Lpart[lb] + Lpart[lb + 32768] + Lpart[lb + 2 * 32768];
    int bb = bh >> 3, h = bh & 7;
    Ob[((size_t)(bb * 2048 + q)) * 512 + h * 64 + d] = f2bf(o / l);
}

// ---------------- output projection GEMM (bf16 in, fp32 out) ----------------
__global__ __launch_bounds__(256) void gemm_out(
        const u16* __restrict__ Ob, const u16* __restrict__ WoT,
        const float* __restrict__ bo, float* __restrict__ out) {
    __shared__ u16 As[64][72];
    __shared__ u16 Bs[64][72];
    int tid = threadIdx.x;
    int m0 = blockIdx.x * 64;
    int n0 = blockIdx.y * 64;
    int lane = tid & 63, w = tid >> 6, lo = lane & 15, hi = lane >> 4;
    floatx4 acc[4] = {};

    for (int kb = 0; kb < 8; kb++) {
        __syncthreads();
        for (int c = tid; c < 512; c += 256) {
            int row = c >> 3, cc = c & 7;
            *(uintx4*)&As[row][cc * 8] =
                *(const uintx4*)&Ob[(size_t)(m0 + row) * 512 + kb * 64 + cc * 8];
            *(uintx4*)&Bs[row][cc * 8] =
                *(const uintx4*)&WoT[(size_t)(n0 + row) * 512 + kb * 64 + cc * 8];
        }
        __syncthreads();
        for (int s = 0; s < 2; s++) {
            bf16x8 a = ld_frag(&As[16 * w + lo][8 * hi + 32 * s]);
            for (int t = 0; t < 4; t++) {
                bf16x8 b = ld_frag(&Bs[16 * t + lo][8 * hi + 32 * s]);
                acc[t] = MFMA16(a, b, acc[t]);
            }
        }
    }
    for (int t = 0; t < 4; t++) {
        int n = n0 + 16 * t + lo;
        float bval = bo[n];
        for (int r = 0; r < 4; r++) {
            int mrow = m0 + 16 * w + 4 * hi + r;
            out[(size_t)mrow * 512 + n] = acc[t][r] + bval;
        }
    }
}

extern "C" void kernel_launch(void* const* d_in, const int* in_sizes, int n_in,
                              void* d_out, int out_size, void* d_ws, size_t ws_size,
                              hipStream_t stream) {
    const float* x     = (const float*)d_in[0];
    const int*   amask = (const int*)d_in[1];
    const int*   gids  = (const int*)d_in[2];
    const int*   dids  = (const int*)d_in[3];
    const float* Wq    = (const float*)d_in[4];
    const float* bq    = (const float*)d_in[5];
    const float* Wk    = (const float*)d_in[6];
    const float* bk    = (const float*)d_in[7];
    const float* Wv    = (const float*)d_in[8];
    const float* bv    = (const float*)d_in[9];
    const float* Wo    = (const float*)d_in[10];
    const float* bo    = (const float*)d_in[11];
    const float* gap_emb = (const float*)d_in[12];
    const float* dur_emb = (const float*)d_in[13];
    float* out = (float*)d_out;

    char* ws = (char*)d_ws;
    u16*   Qe    = (u16*)(ws + 0);            // 8.4 MB
    u16*   Ke    = (u16*)(ws + 8388608);      // 8.4 MB
    u16*   Vt    = (u16*)(ws + 16777216);     // 4.2 MB
    float* Opart = (float*)(ws + 20971520);   // 25.2 MB (3 splits)
    float* Lpart = (float*)(ws + 46137344);   // 0.39 MB
    u16*   Ob    = (u16*)(ws + 46530560);     // 4.2 MB
    u16*   WoT   = (u16*)(ws + 50724864);     // 0.5 MB
    // stage-1 scratch aliased inside Opart (dead before flash_attn writes it)
    u16*   Xb    = (u16*)(ws + 20971520);     // 4 MB
    u16*   WqT   = (u16*)(ws + 25165824);
    u16*   WkT   = (u16*)(ws + 25690112);
    u16*   WvT   = (u16*)(ws + 26214400);

    hipLaunchKernelGGL(cast_x_kernel, dim3(1024), dim3(256), 0, stream, x, Xb);
    hipLaunchKernelGGL(transpose_w_kernel, dim3(1024, 4), dim3(256), 0, stream,
                       Wq, Wk, Wv, Wo, WqT, WkT, WvT, WoT);
    hipLaunchKernelGGL(gemm_qkv, dim3(64, 24), dim3(256), 0, stream,
                       Xb, WqT, WkT, WvT, bq, bk, bv, Qe, Ke, Vt);
    hipLaunchKernelGGL(ext_q_kernel, dim3(128), dim3(256), 0, stream, gids, Qe);
    hipLaunchKernelGGL(ext_k_kernel, dim3(128), dim3(256), 0, stream,
                       gids, dids, amask, gap_emb, dur_emb, Ke);
    hipLaunchKernelGGL(flash_attn, dim3(32, 16, 3), dim3(256), 0, stream,
                       Qe, Ke, Vt, Opart, Lpart);
    hipLaunchKernelGGL(combine_kernel, dim3(8192), dim3(256), 0, stream,
                       Opart, Lpart, Ob);
    hipLaunchKernelGGL(gemm_out, dim3(64, 8), dim3(256), 0, stream,
                       Ob, WoT, bo, out);
}